// Round 9
// baseline (195.295 us; speedup 1.0000x reference)
//
#include <hip/hip_runtime.h>

// SynthesisStage: modulated conv2d w/ adaptive kernel selection.
// B=8, Ci=Co=256, H=W=128, K=3, N=4.
// v9 = v7 structure (best: 190us) with 32x32x16 MFMA (m119 peak shape):
// half the MFMA instructions, +21% matrix ceiling. A-frags direct
// global->VGPR (fragment-ordered wmod, dbuf), XR LDS layout unchanged,
// 1 raw s_barrier per (dh,kb) group, compiler-counted vmcnt.

typedef __attribute__((ext_vector_type(4))) float f32x4;
typedef __attribute__((ext_vector_type(16))) float f32x16;
typedef __attribute__((ext_vector_type(8))) short s16x8;

#define NB   8
#define NCI  256
#define NCO  256
#define NHW  128
#define NKER 4

#define SB0 __builtin_amdgcn_sched_barrier(0)
#define BAR __builtin_amdgcn_s_barrier()
#define WAITL0 asm volatile("s_waitcnt lgkmcnt(0)" ::: "memory")

__device__ __forceinline__ unsigned short f2bf(float f) {
  unsigned int u = __builtin_bit_cast(unsigned int, f);
  u += 0x7FFFu + ((u >> 16) & 1u);          // round-to-nearest-even
  return (unsigned short)(u >> 16);
}

// ---------------------------------------------------------------------------
// Kernel 1: modulated+demodulated weights -> bf16, fragment-direct for
// mfma_32x32x16. Tile T=(b*9+tap)*8+kb is 16KB, shorts laid out as
// [wid 4][ks 2][m 2][lane 64][j 8]; element (co,ci5):
//   wid=co>>6, m=(co>>5)&1, lane=(co&31)+32*((ci5>>3)&1), ks=ci5>>4, j=ci5&7
// conv_k wave wid reads af[ks*2+m] as one dwordx4 at
//   T*16384 + wid*4096 + ks*2048 + m*1024 + lane*16.
// ---------------------------------------------------------------------------
__global__ __launch_bounds__(256) void prep_k(
    const float* __restrict__ weight,    // [N][Co][Ci][3][3]
    const float* __restrict__ styles,    // [B][Ci]
    const float* __restrict__ selector,  // [B][N]
    unsigned short* __restrict__ wmod)   // fragment-ordered, 9.44 MB
{
  int bid = blockIdx.x;
  int b = bid >> 8, co = bid & 255;
  int ci = threadIdx.x;

  float sel[NKER];
#pragma unroll
  for (int n = 0; n < NKER; ++n) sel[n] = selector[b * NKER + n];

  float a[9];
#pragma unroll
  for (int j = 0; j < 9; ++j) a[j] = 0.f;
#pragma unroll
  for (int n = 0; n < NKER; ++n) {
    const float* wp = weight + (size_t)((n * NCO + co) * NCI + ci) * 9;
    float s = sel[n];
#pragma unroll
    for (int j = 0; j < 9; ++j) a[j] += s * wp[j];
  }
  float st = styles[b * NCI + ci];
  float ss = 0.f;
#pragma unroll
  for (int j = 0; j < 9; ++j) { a[j] *= st; ss += a[j] * a[j]; }

  for (int off = 32; off; off >>= 1) ss += __shfl_down(ss, off, 64);
  __shared__ float red[4];
  int wid = threadIdx.x >> 6, lane = threadIdx.x & 63;
  if (lane == 0) red[wid] = ss;
  __syncthreads();
  float tot = red[0] + red[1] + red[2] + red[3];
  float d = rsqrtf(tot + 1e-8f);

  int kb = ci >> 5, ci5 = ci & 31;
  size_t base = (size_t)(co >> 6) * 2048 + (size_t)(ci5 >> 4) * 1024 +
                (size_t)(((co >> 5) & 1) * 512) +
                (size_t)(((co & 31) + ((ci5 >> 3) & 1) * 32) * 8) + (ci5 & 7);
#pragma unroll
  for (int j = 0; j < 9; ++j) {
    size_t T = (size_t)((b * 9 + j) * 8 + kb);
    wmod[(T << 13) + base] = f2bf(a[j] * d);
  }
}

// ---------------------------------------------------------------------------
// Kernel 2: implicit-GEMM conv; A direct-from-global, B via 16KB LDS dbuf.
// block = (b, h); 256 thr = 4 waves, wave tile 64co x 128px; 72 K-tiles.
// Per tile: 2 ksteps x (2co x 4px) mfma_32x32x16.
// ---------------------------------------------------------------------------
__global__ __launch_bounds__(256, 2) void conv_k(
    const float* __restrict__ x,              // [B][Ci][H][W] f32
    const unsigned short* __restrict__ wg,    // fragment-ordered wmod
    const float* __restrict__ noise,          // [B][Co][H][W]
    float* __restrict__ out)                  // [B][Co][H][W]
{
  extern __shared__ __align__(16) char XRs[]; // 2 x 8KB XR dbuf

  int orig = blockIdx.x;             // 1024 blocks
  int b = orig & 7;                  // XCD-resident sample
  int h = orig >> 3;

  int t = threadIdx.x;
  int lane = t & 63;
  int wid = t >> 6;
  int cow = wid << 6;
  int l31 = lane & 31;
  int lh = lane >> 5;                // k 8-group / D row +4 shift

  f32x16 acc[2][4];
#pragma unroll
  for (int m = 0; m < 2; ++m)
#pragma unroll
    for (int n = 0; n < 4; ++n)
#pragma unroll
      for (int e = 0; e < 16; ++e) acc[m][n][e] = 0.f;

  // x staging: thread owns ci-pair (c,c+1) x 8 w's (w = wi + 16*j2)
  int c = ((t >> 4) & 15) * 2;
  int wi = t & 15;
  float xlo[8], xhi[8];
  unsigned xmask = 0xFFFFFFFFu;

  auto issueX = [&](int g) {
    int gc = g < 24 ? g : 23;
    int dh = gc >> 3, kb = gc & 7;
    int hy = h + dh - 1;
    xmask = ((unsigned)hy < 128u) ? 0xFFFFFFFFu : 0u;
    int hyc = hy < 0 ? 0 : (hy > 127 ? 127 : hy);
    const float* base = x + ((size_t)(b * NCI + kb * 32 + c) * NHW + hyc) * NHW + wi;
#pragma unroll
    for (int j2 = 0; j2 < 8; ++j2) {
      xlo[j2] = base[j2 * 16];
      xhi[j2] = base[NHW * NHW + j2 * 16];
    }
  };

  // A-fragments straight from global (fragment-ordered tile, coalesced)
  auto issueAF = [&](int tc, s16x8* af) {    // af[ks*2+m]
    if (tc > 71) tc = 71;
    int g = tc / 3, tap = tc - g * 3;
    int dh = g >> 3, kb = g & 7;
    const char* src = (const char*)wg +
        ((size_t)((b * 9 + dh * 3 + tap) * 8 + kb) << 14) + wid * 4096 + lane * 16;
#pragma unroll
    for (int q = 0; q < 4; ++q)
      af[q] = *(const s16x8*)(src + ((q >> 1) * 2048) + ((q & 1) * 1024));
  };

  auto packXR = [&](int g) {
    char* dstb = XRs + (g & 1) * 8192;
    int slot = (((wi & 1) << 2) + (c >> 3)) ^ ((wi >> 1) & 7);
    char* p0 = dstb + (wi >> 1) * 128 + (slot << 4) + ((c & 7) << 1);
#pragma unroll
    for (int j2 = 0; j2 < 8; ++j2) {
      unsigned pk = ((unsigned)f2bf(xhi[j2]) << 16) | f2bf(xlo[j2]);
      *(unsigned*)(p0 + j2 * 1024) = pk & xmask;  // zero-fill border rows
    }
  };

// B-fragments for 32x32: bf[ks*4+n], px = n*32 + l31 + DW-1,
// ci-chunk cig = ks*2 + lh. Edge clamp+select only at (DW0,n0)/(DW2,n3).
#define PFB(XRBASE, DW, bf)                                              \
  {                                                                      \
    const char* Xb = (XRBASE);                                           \
    _Pragma("unroll")                                                    \
    for (int ks = 0; ks < 2; ++ks) {                                     \
      int cig = ks * 2 + lh;                                             \
      _Pragma("unroll")                                                  \
      for (int n = 0; n < 4; ++n) {                                      \
        int wn = n * 32 + l31 + (DW) - 1;                                \
        if (((DW) == 0 && n == 0) || ((DW) == 2 && n == 3)) {            \
          int wx = wn < 0 ? 0 : (wn > 127 ? 127 : wn);                   \
          int row = wx >> 1;                                             \
          int slot = (((wx & 1) << 2) + cig) ^ (row & 7);                \
          s16x8 bv = *(const s16x8*)(Xb + row * 128 + (slot << 4));      \
          if (wn != wx) { s16x8 z = {0, 0, 0, 0, 0, 0, 0, 0}; bv = z; }  \
          bf[ks * 4 + n] = bv;                                           \
        } else {                                                         \
          int row = wn >> 1;                                             \
          int slot = (((wn & 1) << 2) + cig) ^ (row & 7);                \
          bf[ks * 4 + n] = *(const s16x8*)(Xb + row * 128 + (slot << 4));\
        }                                                                \
      }                                                                  \
    }                                                                    \
  }

#define MFMA16(af, bf)                                                   \
  __builtin_amdgcn_s_setprio(1);                                         \
  _Pragma("unroll")                                                      \
  for (int ks = 0; ks < 2; ++ks)                                         \
    _Pragma("unroll")                                                    \
    for (int m = 0; m < 2; ++m)                                          \
      _Pragma("unroll")                                                  \
      for (int n = 0; n < 4; ++n)                                        \
        acc[m][n] = __builtin_amdgcn_mfma_f32_32x32x16_bf16(             \
            af[ks * 2 + m], bf[ks * 4 + n], acc[m][n], 0, 0, 0);         \
  __builtin_amdgcn_s_setprio(0);

  s16x8 afA[4], afB[4], bf[8];

  // ---- prologue: x(0), af(0)->A; pack XR(0) ----
  issueX(0); SB0;
  issueAF(0, afA); SB0;
  packXR(0);                          // compiler waits x via counted vmcnt

  // ---- main loop: 12 x 6 tiles (2 groups); 1 barrier per group ----
#pragma unroll 1
  for (int gg = 0; gg < 12; ++gg) {
    int g0 = gg * 2, t0 = gg * 6;
    // T0: group g0 (xr buf0), tap0, af=afA
    WAITL0; SB0; BAR; SB0;
    PFB(XRs, 0, bf);
    issueAF(t0 + 1, afB); SB0;
    issueX(g0 + 1); SB0;
    MFMA16(afA, bf);
    // T1: tap1, af=afB
    PFB(XRs, 1, bf);
    issueAF(t0 + 2, afA); SB0;
    MFMA16(afB, bf);
    // T2: tap2, af=afA
    PFB(XRs, 2, bf);
    issueAF(t0 + 3, afB); SB0;
    packXR(g0 + 1);
    MFMA16(afA, bf);
    // T3: group g0+1 (xr buf1), tap0, af=afB
    WAITL0; SB0; BAR; SB0;
    PFB(XRs + 8192, 0, bf);
    issueAF(t0 + 4, afA); SB0;
    issueX(g0 + 2); SB0;
    MFMA16(afB, bf);
    // T4: tap1, af=afA
    PFB(XRs + 8192, 1, bf);
    issueAF(t0 + 5, afB); SB0;
    MFMA16(afA, bf);
    // T5: tap2, af=afB
    PFB(XRs + 8192, 2, bf);
    issueAF(t0 + 6, afA); SB0;
    packXR(g0 + 2);
    MFMA16(afB, bf);
  }

  // epilogue: 32x32 D: col(px)=l31, row(co)=(r&3)+8*(r>>2)+4*lh; fused noise
#pragma unroll
  for (int m = 0; m < 2; ++m) {
#pragma unroll
    for (int n = 0; n < 4; ++n) {
      int px = n * 32 + l31;
#pragma unroll
      for (int r = 0; r < 16; ++r) {
        int co = cow + m * 32 + (r & 3) + 8 * (r >> 2) + 4 * lh;
        size_t idx = ((size_t)(b * NCO + co) * NHW + h) * NHW + px;
        out[idx] = acc[m][n][r] + noise[idx];
      }
    }
  }
}

// ---------------------------------------------------------------------------
extern "C" void kernel_launch(void* const* d_in, const int* in_sizes, int n_in,
                              void* d_out, int out_size, void* d_ws, size_t ws_size,
                              hipStream_t stream) {
  const float* x        = (const float*)d_in[0];
  const float* weight   = (const float*)d_in[1];
  const float* styles   = (const float*)d_in[2];
  const float* selector = (const float*)d_in[3];
  const float* noise    = (const float*)d_in[4];
  float* out = (float*)d_out;

  // workspace: ONLY wmod (fragment-ordered) = 9,437,184 bytes
  unsigned short* wmod = (unsigned short*)d_ws;

  hipLaunchKernelGGL(prep_k, dim3(NB * NCO), dim3(256), 0, stream,
                     weight, styles, selector, wmod);
  hipLaunchKernelGGL(conv_k, dim3(NB * NHW), dim3(256), 16 * 1024, stream,
                     x, wmod, noise, out);
}